// Round 1
// baseline (618.905 us; speedup 1.0000x reference)
//
#include <hip/hip_runtime.h>
#include <hip/hip_bf16.h>
#include <math.h>

// MoNet / GMMConv 2-layer GNN, fp32.
// N=50000, E=800000, F=128, H=64, C=16, K=8, D=2
// Pipeline: gx1=x@g1_w -> edge pass1 (gauss-weighted gather + atomic scatter, deg)
//   -> h=ELU(agg1/deg + x@root1_w + b1) -> gx2=h@g2_w -> edge pass2
//   -> out=log_softmax(agg2/deg + h@root2_w + b2)

#define NF 128   // input features
#define NH 64    // hidden
#define NC 16    // classes
#define NK 8     // gaussian kernels

// ---------------- GEMM: gx1 = x[M,128] @ g1_w[128,512] ----------------
__global__ __launch_bounds__(256) void gemm1_kernel(
    const float* __restrict__ A, const float* __restrict__ B,
    float* __restrict__ C, int M) {
  __shared__ float As[64][132];   // padded: bank-conflict-free strided reads
  __shared__ float Bs[128][64];
  const int m0 = (int)blockIdx.x * 64;
  const int n0 = (int)blockIdx.y * 64;
  const int t = threadIdx.x;

  // Load A tile 64x128 (2048 float4, 8/thread), coalesced 64B segments.
  #pragma unroll
  for (int it = 0; it < 8; ++it) {
    int fidx = it * 256 + t;
    int m = fidx >> 5;              // 0..63
    int kk = (fidx & 31) << 2;      // 0..124
    float4 v = make_float4(0.f, 0.f, 0.f, 0.f);
    if (m0 + m < M) v = *(const float4*)(A + (size_t)(m0 + m) * NF + kk);
    *(float4*)(&As[m][kk]) = v;
  }
  // Load B tile 128x64 (2048 float4, 8/thread), coalesced 256B segments.
  #pragma unroll
  for (int it = 0; it < 8; ++it) {
    int fidx = it * 256 + t;
    int kk = fidx >> 4;             // 0..127
    int nn = (fidx & 15) << 2;      // 0..60
    float4 v = *(const float4*)(B + (size_t)kk * 512 + n0 + nn);
    *(float4*)(&Bs[kk][nn]) = v;
  }
  __syncthreads();

  const int tx = t & 15, ty = t >> 4;
  const int mb = ty * 4, nb = tx * 4;
  float acc[4][4];
  #pragma unroll
  for (int i = 0; i < 4; ++i)
    #pragma unroll
    for (int j = 0; j < 4; ++j) acc[i][j] = 0.f;

  #pragma unroll 4
  for (int k = 0; k < 128; k += 4) {
    float4 a[4], b[4];
    #pragma unroll
    for (int i = 0; i < 4; ++i) a[i] = *(const float4*)(&As[mb + i][k]);
    #pragma unroll
    for (int kk = 0; kk < 4; ++kk) b[kk] = *(const float4*)(&Bs[k + kk][nb]);
    #pragma unroll
    for (int i = 0; i < 4; ++i) {
      const float a0 = a[i].x, a1 = a[i].y, a2 = a[i].z, a3 = a[i].w;
      acc[i][0] = fmaf(a0, b[0].x, acc[i][0]); acc[i][1] = fmaf(a0, b[0].y, acc[i][1]);
      acc[i][2] = fmaf(a0, b[0].z, acc[i][2]); acc[i][3] = fmaf(a0, b[0].w, acc[i][3]);
      acc[i][0] = fmaf(a1, b[1].x, acc[i][0]); acc[i][1] = fmaf(a1, b[1].y, acc[i][1]);
      acc[i][2] = fmaf(a1, b[1].z, acc[i][2]); acc[i][3] = fmaf(a1, b[1].w, acc[i][3]);
      acc[i][0] = fmaf(a2, b[2].x, acc[i][0]); acc[i][1] = fmaf(a2, b[2].y, acc[i][1]);
      acc[i][2] = fmaf(a2, b[2].z, acc[i][2]); acc[i][3] = fmaf(a2, b[2].w, acc[i][3]);
      acc[i][0] = fmaf(a3, b[3].x, acc[i][0]); acc[i][1] = fmaf(a3, b[3].y, acc[i][1]);
      acc[i][2] = fmaf(a3, b[3].z, acc[i][2]); acc[i][3] = fmaf(a3, b[3].w, acc[i][3]);
    }
  }
  #pragma unroll
  for (int i = 0; i < 4; ++i) {
    int r = m0 + mb + i;
    if (r < M) {
      float4 v = make_float4(acc[i][0], acc[i][1], acc[i][2], acc[i][3]);
      *(float4*)(C + (size_t)r * 512 + n0 + nb) = v;
    }
  }
}

// ---------------- Edge pass 1: 1 wave per edge, Fout=64 ----------------
__global__ __launch_bounds__(256) void edge1_kernel(
    const float* __restrict__ gx, const int* __restrict__ row,
    const int* __restrict__ col, const float* __restrict__ eattr,
    const float* __restrict__ mu, const float* __restrict__ sigma,
    float* __restrict__ agg, float* __restrict__ deg, int E) {
  const int lane = threadIdx.x & 63;
  const int e = blockIdx.x * 4 + (threadIdx.x >> 6);
  if (e >= E) return;
  const int r = row[e];
  const int c = col[e];
  float w = 0.f;
  if (lane < NK) {
    float p0 = eattr[2 * e], p1 = eattr[2 * e + 1];
    float m0 = mu[2 * lane], m1 = mu[2 * lane + 1];
    float s0 = sigma[2 * lane], s1 = sigma[2 * lane + 1];
    float d0 = p0 - m0, d1 = p1 - m1;
    w = __expf(-0.5f * (d0 * d0 / (1e-15f + s0 * s0) +
                        d1 * d1 / (1e-15f + s1 * s1)));
  }
  const float* g = gx + (size_t)r * (NK * NH) + lane;
  float msg = 0.f;
  #pragma unroll
  for (int k = 0; k < NK; ++k) {
    float wk = __shfl(w, k, 64);
    msg = fmaf(wk, g[k * NH], msg);
  }
  atomicAdd(agg + (size_t)c * NH + lane, msg);
  if (lane == 0) atomicAdd(deg + c, 1.0f);
}

// ---------------- Edge pass 2: 16 lanes per edge, Fout=16 ----------------
__global__ __launch_bounds__(256) void edge2_kernel(
    const float* __restrict__ gx, const int* __restrict__ row,
    const int* __restrict__ col, const float* __restrict__ eattr,
    const float* __restrict__ mu, const float* __restrict__ sigma,
    float* __restrict__ agg, int E) {
  const int id = threadIdx.x & 15;
  const int e = blockIdx.x * 16 + (threadIdx.x >> 4);
  if (e >= E) return;
  const int r = row[e];
  const int c = col[e];
  float w = 0.f;
  if (id < NK) {
    float p0 = eattr[2 * e], p1 = eattr[2 * e + 1];
    float m0 = mu[2 * id], m1 = mu[2 * id + 1];
    float s0 = sigma[2 * id], s1 = sigma[2 * id + 1];
    float d0 = p0 - m0, d1 = p1 - m1;
    w = __expf(-0.5f * (d0 * d0 / (1e-15f + s0 * s0) +
                        d1 * d1 / (1e-15f + s1 * s1)));
  }
  const float* g = gx + (size_t)r * (NK * NC) + id;
  float msg = 0.f;
  #pragma unroll
  for (int k = 0; k < NK; ++k) {
    float wk = __shfl(w, k, 16);
    msg = fmaf(wk, g[k * NC], msg);
  }
  atomicAdd(agg + (size_t)c * NC + id, msg);
}

// ------------- combine1: h = ELU(agg/deg + x@root1_w + b1) -------------
__global__ __launch_bounds__(256) void combine1_kernel(
    const float* __restrict__ x, const float* __restrict__ agg,
    const float* __restrict__ deg, const float* __restrict__ rw,
    const float* __restrict__ bias, float* __restrict__ h, int N) {
  __shared__ float xs[4][NF];
  const int wv = threadIdx.x >> 6, lane = threadIdx.x & 63;
  const int n = blockIdx.x * 4 + wv;
  if (n < N) {
    xs[wv][lane] = x[(size_t)n * NF + lane];
    xs[wv][lane + 64] = x[(size_t)n * NF + 64 + lane];
  }
  __syncthreads();
  if (n >= N) return;
  float acc = 0.f;
  #pragma unroll 8
  for (int f = 0; f < NF; ++f) acc = fmaf(xs[wv][f], rw[f * NH + lane], acc);
  float d = fmaxf(deg[n], 1.0f);
  float v = agg[(size_t)n * NH + lane] / d + acc + bias[lane];
  h[(size_t)n * NH + lane] = v > 0.f ? v : expm1f(v);
}

// ---------------- gemm2: gx2 = h[N,64] @ g2_w[64,128] ----------------
__global__ __launch_bounds__(256) void gemm2_kernel(
    const float* __restrict__ h, const float* __restrict__ w,
    float* __restrict__ gx2, int N) {
  __shared__ float hs[4][NH];
  const int wv = threadIdx.x >> 6, lane = threadIdx.x & 63;
  const int n = blockIdx.x * 4 + wv;
  if (n < N) hs[wv][lane] = h[(size_t)n * NH + lane];
  __syncthreads();
  if (n >= N) return;
  float a0 = 0.f, a1 = 0.f;
  #pragma unroll 8
  for (int f = 0; f < NH; ++f) {
    float hv = hs[wv][f];
    a0 = fmaf(hv, w[f * 128 + lane], a0);
    a1 = fmaf(hv, w[f * 128 + 64 + lane], a1);
  }
  gx2[(size_t)n * 128 + lane] = a0;
  gx2[(size_t)n * 128 + 64 + lane] = a1;
}

// ------ combine2 + log_softmax: out = lsm(agg2/deg + h@root2_w + b2) ------
__global__ __launch_bounds__(256) void combine2_kernel(
    const float* __restrict__ h, const float* __restrict__ agg2,
    const float* __restrict__ deg, const float* __restrict__ rw,
    const float* __restrict__ bias, float* __restrict__ out, int N) {
  __shared__ float hs[4][NH];
  const int wv = threadIdx.x >> 6, lane = threadIdx.x & 63;
  const int n = blockIdx.x * 4 + wv;
  if (n < N) hs[wv][lane] = h[(size_t)n * NH + lane];
  __syncthreads();
  if (n >= N) return;
  const int c = lane & 15, part = lane >> 4;
  float acc = 0.f;
  #pragma unroll
  for (int j = 0; j < 16; ++j) {
    int f = part * 16 + j;
    acc = fmaf(hs[wv][f], rw[f * NC + c], acc);
  }
  acc += __shfl_xor(acc, 16, 64);
  acc += __shfl_xor(acc, 32, 64);
  float d = fmaxf(deg[n], 1.0f);
  float v = agg2[(size_t)n * NC + c] / d + acc + bias[c];
  // log_softmax over the 16-lane group (all 4 groups hold identical v)
  float m = v;
  #pragma unroll
  for (int off = 8; off >= 1; off >>= 1) m = fmaxf(m, __shfl_xor(m, off, 16));
  float s = __expf(v - m);
  #pragma unroll
  for (int off = 8; off >= 1; off >>= 1) s += __shfl_xor(s, off, 16);
  if (part == 0) out[(size_t)n * NC + c] = v - m - __logf(s);
}

extern "C" void kernel_launch(void* const* d_in, const int* in_sizes, int n_in,
                              void* d_out, int out_size, void* d_ws, size_t ws_size,
                              hipStream_t stream) {
  const float* x     = (const float*)d_in[0];
  const int*   eidx  = (const int*)d_in[1];
  const float* eattr = (const float*)d_in[2];
  const float* g1w   = (const float*)d_in[3];
  const float* mu1   = (const float*)d_in[4];
  const float* sg1   = (const float*)d_in[5];
  const float* r1w   = (const float*)d_in[6];
  const float* b1    = (const float*)d_in[7];
  const float* g2w   = (const float*)d_in[8];
  const float* mu2   = (const float*)d_in[9];
  const float* sg2   = (const float*)d_in[10];
  const float* r2w   = (const float*)d_in[11];
  const float* b2    = (const float*)d_in[12];

  const int N = in_sizes[0] / NF;       // 50000
  const int E = in_sizes[1] / 2;        // 800000
  const int* row = eidx;
  const int* col = eidx + E;

  // Workspace layout (floats):
  //   gx   : N*512 (gx1; reused as gx2 which needs only N*128)
  //   agg1 : N*64
  //   agg2 : N*16
  //   deg  : N
  //   h    : N*64
  float* ws   = (float*)d_ws;
  float* gx   = ws;
  float* agg1 = gx + (size_t)N * 512;
  float* agg2 = agg1 + (size_t)N * NH;
  float* degb = agg2 + (size_t)N * NC;
  float* hbuf = degb + N;

  // zero the accumulators (agg1|agg2|deg are contiguous)
  hipMemsetAsync(agg1, 0, (size_t)(N * NH + N * NC + N) * sizeof(float), stream);

  dim3 g1grid((N + 63) / 64, 8);
  gemm1_kernel<<<g1grid, 256, 0, stream>>>(x, g1w, gx, N);
  edge1_kernel<<<(E + 3) / 4, 256, 0, stream>>>(gx, row, col, eattr, mu1, sg1,
                                                agg1, degb, E);
  combine1_kernel<<<(N + 3) / 4, 256, 0, stream>>>(x, agg1, degb, r1w, b1,
                                                   hbuf, N);
  gemm2_kernel<<<(N + 3) / 4, 256, 0, stream>>>(hbuf, g2w, gx, N);
  edge2_kernel<<<(E + 15) / 16, 256, 0, stream>>>(gx, row, col, eattr, mu2,
                                                  sg2, agg2, E);
  combine2_kernel<<<(N + 3) / 4, 256, 0, stream>>>(hbuf, agg2, degb, r2w, b2,
                                                   (float*)d_out, N);
}

// Round 2
// 572.319 us; speedup vs baseline: 1.0814x; 1.0814x over previous
//
#include <hip/hip_runtime.h>
#include <hip/hip_bf16.h>
#include <math.h>

// MoNet / GMMConv 2-layer GNN on MI355X.
// N=50000, E=800000, F=128, H=64, C=16, K=8, D=2
// R2: CSR (sort edges by target col) -> node-centric register aggregation,
//     bf16 gather buffers (gx1/gx2), fused combine epilogues.

#define NF 128
#define NH 64
#define NC 16
#define NK 8

__device__ inline ushort f2bu(float x) {
  __hip_bfloat16 h = __float2bfloat16(x);
  return *(ushort*)&h;
}

// ---------------- CSR build ----------------
__global__ __launch_bounds__(256) void hist_kernel(const int* __restrict__ col,
                                                   int* __restrict__ counts, int E) {
  int e = blockIdx.x * 256 + threadIdx.x;
  if (e < E) atomicAdd(&counts[col[e]], 1);
}

__global__ __launch_bounds__(1024) void scan_kernel(const int* __restrict__ counts,
                                                    int* __restrict__ starts,
                                                    int* __restrict__ cursor, int N) {
  __shared__ int carry;
  __shared__ int wsum[16];
  const int t = threadIdx.x, lane = t & 63, wv = t >> 6;
  if (t == 0) carry = 0;
  __syncthreads();
  for (int base = 0; base < N; base += 1024) {
    int i = base + t;
    int v = (i < N) ? counts[i] : 0;
    int s = v;
    #pragma unroll
    for (int off = 1; off < 64; off <<= 1) {
      int u = __shfl_up(s, off, 64);
      if (lane >= off) s += u;
    }
    if (lane == 63) wsum[wv] = s;
    __syncthreads();
    if (t == 0) {
      int a = 0;
      #pragma unroll
      for (int j = 0; j < 16; ++j) { int tmp = wsum[j]; wsum[j] = a; a += tmp; }
    }
    __syncthreads();
    int excl = (s - v) + wsum[wv] + carry;   // reads carry
    if (i < N) { starts[i] = excl; cursor[i] = excl; }
    __syncthreads();
    if (t == 1023) carry = excl + v;         // new running total
    __syncthreads();
  }
  if (t == 0) starts[N] = carry;
}

// Packed record per edge slot: {bitcast(row), p0, p1, unused}
__global__ __launch_bounds__(256) void fill_kernel(const int* __restrict__ row,
                                                   const int* __restrict__ col,
                                                   const float* __restrict__ eattr,
                                                   int* __restrict__ cursor,
                                                   float4* __restrict__ recs, int E) {
  int e = blockIdx.x * 256 + threadIdx.x;
  if (e >= E) return;
  int c = col[e];
  int pos = atomicAdd(&cursor[c], 1);
  recs[pos] = make_float4(__int_as_float(row[e]), eattr[2 * e], eattr[2 * e + 1], 0.f);
}

// ---------------- GEMM1: gx1 = x[M,128] @ g1_w[128,512] -> bf16 ----------------
__global__ __launch_bounds__(256) void gemm1_kernel(
    const float* __restrict__ A, const float* __restrict__ B,
    ushort* __restrict__ C, int M) {
  __shared__ float As[64][132];
  __shared__ float Bs[128][64];
  const int m0 = (int)blockIdx.x * 64;
  const int n0 = (int)blockIdx.y * 64;
  const int t = threadIdx.x;

  #pragma unroll
  for (int it = 0; it < 8; ++it) {
    int fidx = it * 256 + t;
    int m = fidx >> 5;
    int kk = (fidx & 31) << 2;
    float4 v = make_float4(0.f, 0.f, 0.f, 0.f);
    if (m0 + m < M) v = *(const float4*)(A + (size_t)(m0 + m) * NF + kk);
    *(float4*)(&As[m][kk]) = v;
  }
  #pragma unroll
  for (int it = 0; it < 8; ++it) {
    int fidx = it * 256 + t;
    int kk = fidx >> 4;
    int nn = (fidx & 15) << 2;
    float4 v = *(const float4*)(B + (size_t)kk * 512 + n0 + nn);
    *(float4*)(&Bs[kk][nn]) = v;
  }
  __syncthreads();

  const int tx = t & 15, ty = t >> 4;
  const int mb = ty * 4, nb = tx * 4;
  float acc[4][4];
  #pragma unroll
  for (int i = 0; i < 4; ++i)
    #pragma unroll
    for (int j = 0; j < 4; ++j) acc[i][j] = 0.f;

  #pragma unroll 4
  for (int k = 0; k < 128; k += 4) {
    float4 a[4], b[4];
    #pragma unroll
    for (int i = 0; i < 4; ++i) a[i] = *(const float4*)(&As[mb + i][k]);
    #pragma unroll
    for (int kk = 0; kk < 4; ++kk) b[kk] = *(const float4*)(&Bs[k + kk][nb]);
    #pragma unroll
    for (int i = 0; i < 4; ++i) {
      const float a0 = a[i].x, a1 = a[i].y, a2 = a[i].z, a3 = a[i].w;
      acc[i][0] = fmaf(a0, b[0].x, acc[i][0]); acc[i][1] = fmaf(a0, b[0].y, acc[i][1]);
      acc[i][2] = fmaf(a0, b[0].z, acc[i][2]); acc[i][3] = fmaf(a0, b[0].w, acc[i][3]);
      acc[i][0] = fmaf(a1, b[1].x, acc[i][0]); acc[i][1] = fmaf(a1, b[1].y, acc[i][1]);
      acc[i][2] = fmaf(a1, b[1].z, acc[i][2]); acc[i][3] = fmaf(a1, b[1].w, acc[i][3]);
      acc[i][0] = fmaf(a2, b[2].x, acc[i][0]); acc[i][1] = fmaf(a2, b[2].y, acc[i][1]);
      acc[i][2] = fmaf(a2, b[2].z, acc[i][2]); acc[i][3] = fmaf(a2, b[2].w, acc[i][3]);
      acc[i][0] = fmaf(a3, b[3].x, acc[i][0]); acc[i][1] = fmaf(a3, b[3].y, acc[i][1]);
      acc[i][2] = fmaf(a3, b[3].z, acc[i][2]); acc[i][3] = fmaf(a3, b[3].w, acc[i][3]);
    }
  }
  #pragma unroll
  for (int i = 0; i < 4; ++i) {
    int r = m0 + mb + i;
    if (r < M) {
      ushort4 p;
      p.x = f2bu(acc[i][0]); p.y = f2bu(acc[i][1]);
      p.z = f2bu(acc[i][2]); p.w = f2bu(acc[i][3]);
      *(ushort4*)(C + (size_t)r * 512 + n0 + nb) = p;
    }
  }
}

// ------- node1: CSR aggregate + mean + x@root1_w + bias -> ELU -> h -------
// one wave per node
__global__ __launch_bounds__(256) void node1_kernel(
    const __hip_bfloat16* __restrict__ gx, const float4* __restrict__ recs,
    const int* __restrict__ starts, const float* __restrict__ x,
    const float* __restrict__ rw, const float* __restrict__ bias,
    const float* __restrict__ mu, const float* __restrict__ sigma,
    float* __restrict__ h, int N) {
  const int lane = threadIdx.x & 63, wv = threadIdx.x >> 6;
  const int n = blockIdx.x * 4 + wv;
  __shared__ float xs[4][NF];
  if (n < N) {
    xs[wv][lane] = x[(size_t)n * NF + lane];
    xs[wv][lane + 64] = x[(size_t)n * NF + 64 + lane];
  }
  __syncthreads();
  if (n >= N) return;
  const int kk = lane & 7;
  const float m0 = mu[2 * kk], m1 = mu[2 * kk + 1];
  const float s0 = sigma[2 * kk], s1 = sigma[2 * kk + 1];
  const float i0 = -0.5f / (1e-15f + s0 * s0), i1 = -0.5f / (1e-15f + s1 * s1);
  const int b = starts[n], e2 = starts[n + 1];
  float msg = 0.f;
  for (int i = b; i < e2; ++i) {
    float4 rec = recs[i];
    int r = __float_as_int(rec.x);
    float d0 = rec.y - m0, d1 = rec.z - m1;
    float w = __expf(d0 * d0 * i0 + d1 * d1 * i1);
    const __hip_bfloat16* g = gx + (size_t)r * (NK * NH) + lane;
    #pragma unroll
    for (int k = 0; k < NK; ++k) {
      float wk = __shfl(w, k, 64);
      msg = fmaf(wk, __bfloat162float(g[k * NH]), msg);
    }
  }
  float cnt = (float)(e2 - b);
  msg /= fmaxf(cnt, 1.f);
  float rt = 0.f;
  #pragma unroll 8
  for (int f = 0; f < NF; ++f) rt = fmaf(xs[wv][f], rw[f * NH + lane], rt);
  float v = msg + rt + bias[lane];
  h[(size_t)n * NH + lane] = v > 0.f ? v : expm1f(v);
}

// ---------------- gemm2: gx2 = h[N,64] @ g2_w[64,128] -> bf16 ----------------
__global__ __launch_bounds__(256) void gemm2_kernel(
    const float* __restrict__ h, const float* __restrict__ w,
    ushort* __restrict__ gx2, int N) {
  __shared__ float hs[4][NH];
  const int wv = threadIdx.x >> 6, lane = threadIdx.x & 63;
  const int n = blockIdx.x * 4 + wv;
  if (n < N) hs[wv][lane] = h[(size_t)n * NH + lane];
  __syncthreads();
  if (n >= N) return;
  float a0 = 0.f, a1 = 0.f;
  #pragma unroll 8
  for (int f = 0; f < NH; ++f) {
    float hv = hs[wv][f];
    a0 = fmaf(hv, w[f * 128 + lane], a0);
    a1 = fmaf(hv, w[f * 128 + 64 + lane], a1);
  }
  gx2[(size_t)n * 128 + lane] = f2bu(a0);
  gx2[(size_t)n * 128 + 64 + lane] = f2bu(a1);
}

// -- node2: CSR aggregate + mean + h@root2_w + bias -> log_softmax -> out --
// 16 lanes per node, 16 nodes per block
__global__ __launch_bounds__(256) void node2_kernel(
    const __hip_bfloat16* __restrict__ gx, const float4* __restrict__ recs,
    const int* __restrict__ starts, const float* __restrict__ h,
    const float* __restrict__ rw, const float* __restrict__ bias,
    const float* __restrict__ mu, const float* __restrict__ sigma,
    float* __restrict__ out, int N) {
  const int t = threadIdx.x;
  const int id = t & 15, grp = t >> 4;
  const int n = blockIdx.x * 16 + grp;
  __shared__ float hs[16][NH];
  {
    int nb = blockIdx.x * 16;
    #pragma unroll
    for (int i = t; i < 16 * NH; i += 256) {
      int rr = i >> 6, cc = i & 63;
      hs[rr][cc] = (nb + rr < N) ? h[(size_t)(nb + rr) * NH + cc] : 0.f;
    }
  }
  __syncthreads();
  if (n >= N) return;
  const int kk = id & 7;
  const float m0 = mu[2 * kk], m1 = mu[2 * kk + 1];
  const float s0 = sigma[2 * kk], s1 = sigma[2 * kk + 1];
  const float i0 = -0.5f / (1e-15f + s0 * s0), i1 = -0.5f / (1e-15f + s1 * s1);
  const int b = starts[n], e2 = starts[n + 1];
  float msg = 0.f;
  for (int i = b; i < e2; ++i) {
    float4 rec = recs[i];
    int r = __float_as_int(rec.x);
    float d0 = rec.y - m0, d1 = rec.z - m1;
    float w = __expf(d0 * d0 * i0 + d1 * d1 * i1);
    const __hip_bfloat16* g = gx + (size_t)r * (NK * NC) + id;
    #pragma unroll
    for (int k = 0; k < NK; ++k) {
      float wk = __shfl(w, k, 16);
      msg = fmaf(wk, __bfloat162float(g[k * NC]), msg);
    }
  }
  float cnt = (float)(e2 - b);
  msg /= fmaxf(cnt, 1.f);
  float rt = 0.f;
  #pragma unroll
  for (int f = 0; f < NH; ++f) rt = fmaf(hs[grp][f], rw[f * NC + id], rt);
  float v = msg + rt + bias[id];
  float mx = v;
  #pragma unroll
  for (int off = 8; off >= 1; off >>= 1) mx = fmaxf(mx, __shfl_xor(mx, off, 16));
  float sum = __expf(v - mx);
  #pragma unroll
  for (int off = 8; off >= 1; off >>= 1) sum += __shfl_xor(sum, off, 16);
  out[(size_t)n * NC + id] = v - mx - __logf(sum);
}

extern "C" void kernel_launch(void* const* d_in, const int* in_sizes, int n_in,
                              void* d_out, int out_size, void* d_ws, size_t ws_size,
                              hipStream_t stream) {
  const float* x     = (const float*)d_in[0];
  const int*   eidx  = (const int*)d_in[1];
  const float* eattr = (const float*)d_in[2];
  const float* g1w   = (const float*)d_in[3];
  const float* mu1   = (const float*)d_in[4];
  const float* sg1   = (const float*)d_in[5];
  const float* r1w   = (const float*)d_in[6];
  const float* b1    = (const float*)d_in[7];
  const float* g2w   = (const float*)d_in[8];
  const float* mu2   = (const float*)d_in[9];
  const float* sg2   = (const float*)d_in[10];
  const float* r2w   = (const float*)d_in[11];
  const float* b2    = (const float*)d_in[12];

  const int N = in_sizes[0] / NF;   // 50000
  const int E = in_sizes[1] / 2;    // 800000
  const int* row = eidx;
  const int* col = eidx + E;

  // Workspace layout:
  //   recs   : E float4            (12.8 MB)
  //   gxh    : N*512 bf16          (51.2 MB; reused as gx2 N*128 bf16)
  //   hbuf   : N*64 float          (12.8 MB)
  //   counts : N int, starts: N+1 int, cursor: N int
  float4* recs = (float4*)d_ws;
  __hip_bfloat16* gxh = (__hip_bfloat16*)(recs + (size_t)E);
  float* hbuf = (float*)(gxh + (size_t)N * 512);
  int* counts = (int*)(hbuf + (size_t)N * NH);
  int* starts = counts + N;
  int* cursor = starts + N + 1;

  hipMemsetAsync(counts, 0, (size_t)N * sizeof(int), stream);
  hist_kernel<<<(E + 255) / 256, 256, 0, stream>>>(col, counts, E);
  scan_kernel<<<1, 1024, 0, stream>>>(counts, starts, cursor, N);
  fill_kernel<<<(E + 255) / 256, 256, 0, stream>>>(row, col, eattr, cursor, recs, E);

  dim3 g1grid((N + 63) / 64, 8);
  gemm1_kernel<<<g1grid, 256, 0, stream>>>(x, g1w, (ushort*)gxh, N);
  node1_kernel<<<(N + 3) / 4, 256, 0, stream>>>(gxh, recs, starts, x, r1w, b1,
                                                mu1, sg1, hbuf, N);
  gemm2_kernel<<<(N + 3) / 4, 256, 0, stream>>>(hbuf, g2w, (ushort*)gxh, N);
  node2_kernel<<<(N + 15) / 16, 256, 0, stream>>>(gxh, recs, starts, hbuf, r2w,
                                                  b2, mu2, sg2, (float*)d_out, N);
}

// Round 3
// 425.003 us; speedup vs baseline: 1.4562x; 1.3466x over previous
//
#include <hip/hip_runtime.h>
#include <hip/hip_bf16.h>
#include <math.h>

// MoNet / GMMConv 2-layer GNN on MI355X (gfx950).
// R3: Z-reformulation. Edge phase gathers x (bf16) instead of gx:
//   Z[c,k,f] = (1/deg_c) sum_e w_ek * x[r_e,f]   (gather 256B/edge, not 1KB)
//   msg = Z @ reshaped(g1_w)  as bf16 MFMA GEMM, with x|root_w folded in as
//   extra K columns and bias+ELU (layer1) / bias+log_softmax (layer2) fused
//   into the GEMM epilogue. gemm1/gemm2/combine1/combine2/node1/node2 all gone.

#define NF 128
#define NH 64
#define NC 16
#define NK 8

typedef __bf16 v8bf __attribute__((ext_vector_type(8)));
typedef float v4f __attribute__((ext_vector_type(4)));

__device__ inline ushort f2bu(float x) {
  __hip_bfloat16 h = __float2bfloat16(x);
  return *(ushort*)&h;
}
__device__ inline float bu2f(ushort u) {
  unsigned int x = ((unsigned int)u) << 16;
  return __uint_as_float(x);
}
__device__ inline v8bf ld_frag(const ushort* p) {
  uint4 u = *(const uint4*)p;
  return __builtin_bit_cast(v8bf, u);
}

// ---------------- CSR build ----------------
__global__ __launch_bounds__(256) void hist_kernel(const int* __restrict__ col,
                                                   int* __restrict__ counts, int E) {
  int e = blockIdx.x * 256 + threadIdx.x;
  if (e < E) atomicAdd(&counts[col[e]], 1);
}

__global__ __launch_bounds__(1024) void scan_kernel(const int* __restrict__ counts,
                                                    int* __restrict__ starts,
                                                    int* __restrict__ cursor, int N) {
  __shared__ int carry;
  __shared__ int wsum[16];
  const int t = threadIdx.x, lane = t & 63, wv = t >> 6;
  if (t == 0) carry = 0;
  __syncthreads();
  for (int base = 0; base < N; base += 1024) {
    int i = base + t;
    int v = (i < N) ? counts[i] : 0;
    int s = v;
    #pragma unroll
    for (int off = 1; off < 64; off <<= 1) {
      int u = __shfl_up(s, off, 64);
      if (lane >= off) s += u;
    }
    if (lane == 63) wsum[wv] = s;
    __syncthreads();
    if (t == 0) {
      int a = 0;
      #pragma unroll
      for (int j = 0; j < 16; ++j) { int tmp = wsum[j]; wsum[j] = a; a += tmp; }
    }
    __syncthreads();
    int excl = (s - v) + wsum[wv] + carry;
    if (i < N) { starts[i] = excl; cursor[i] = excl; }
    __syncthreads();
    if (t == 1023) carry = excl + v;
    __syncthreads();
  }
  if (t == 0) starts[N] = carry;
}

__global__ __launch_bounds__(256) void fill_kernel(const int* __restrict__ row,
                                                   const int* __restrict__ col,
                                                   const float* __restrict__ eattr,
                                                   int* __restrict__ cursor,
                                                   float4* __restrict__ recs, int E) {
  int e = blockIdx.x * 256 + threadIdx.x;
  if (e >= E) return;
  int c = col[e];
  int pos = atomicAdd(&cursor[c], 1);
  recs[pos] = make_float4(__int_as_float(row[e]), eattr[2 * e], eattr[2 * e + 1], 0.f);
}

// ------------- prep: reshape+cast weights to bf16, transposed -------------
// W1t[h][j] (64 x 1152): j<1024 -> g1w[f=j&127][ (j>>7)*64 + h ]; j>=1024 -> r1w[j-1024][h]
// W2t[c][j] (16 x 576):  j<512  -> g2w[f=j&63 ][ (j>>6)*16 + c ]; j>=512  -> r2w[j-512][c]
__global__ __launch_bounds__(256) void prep_kernel(
    const float* __restrict__ g1w, const float* __restrict__ r1w,
    const float* __restrict__ g2w, const float* __restrict__ r2w,
    ushort* __restrict__ W1t, ushort* __restrict__ W2t) {
  int i = blockIdx.x * 256 + threadIdx.x;
  if (i < 64 * 1152) {
    int h = i / 1152, j = i % 1152;
    float v = (j < 1024) ? g1w[(size_t)(j & 127) * 512 + (j >> 7) * 64 + h]
                         : r1w[(size_t)(j - 1024) * 64 + h];
    W1t[i] = f2bu(v);
  } else {
    int i2 = i - 64 * 1152;
    if (i2 < 16 * 576) {
      int c = i2 / 576, j = i2 % 576;
      float v = (j < 512) ? g2w[(size_t)(j & 63) * 128 + (j >> 6) * 16 + c]
                          : r2w[(size_t)(j - 512) * 16 + c];
      W2t[i2] = f2bu(v);
    }
  }
}

// ---- cast x -> bf16 into A1 columns [1024..1151] (row stride 1152) ----
__global__ __launch_bounds__(256) void cast_x_kernel(const float* __restrict__ x,
                                                     ushort* __restrict__ A1, int N) {
  int idx = blockIdx.x * 256 + threadIdx.x;
  if (idx >= N * 32) return;
  int n = idx >> 5, c4 = idx & 31;
  float4 v = ((const float4*)x)[idx];
  ushort4 o;
  o.x = f2bu(v.x); o.y = f2bu(v.y); o.z = f2bu(v.z); o.w = f2bu(v.w);
  *(ushort4*)(A1 + (size_t)n * 1152 + 1024 + c4 * 4) = o;
}

// ---- z1: Z[c, k*128+f] = (1/deg) sum_e w_ek * x_bf[r_e, f]  (wave/node) ----
__global__ __launch_bounds__(256) void z1_kernel(
    ushort* __restrict__ A1, const float4* __restrict__ recs,
    const int* __restrict__ starts, const float* __restrict__ mu,
    const float* __restrict__ sg, int N) {
  const int lane = threadIdx.x & 63, wv = threadIdx.x >> 6;
  const int n = blockIdx.x * 4 + wv;
  if (n >= N) return;
  const int kk = lane & 7;
  const float m0 = mu[2 * kk], m1 = mu[2 * kk + 1];
  const float s0 = sg[2 * kk], s1 = sg[2 * kk + 1];
  const float i0 = -0.5f / (1e-15f + s0 * s0), i1 = -0.5f / (1e-15f + s1 * s1);
  const int b = starts[n], e = starts[n + 1];
  float acc0[8], acc1[8];
  #pragma unroll
  for (int k = 0; k < 8; ++k) { acc0[k] = 0.f; acc1[k] = 0.f; }
  if (b < e) {
    float4 rec = recs[b];
    for (int i = b; i < e; ++i) {
      float4 nxt = rec;
      if (i + 1 < e) nxt = recs[i + 1];
      int r = __float_as_int(rec.x);
      float d0 = rec.y - m0, d1 = rec.z - m1;
      float w = __expf(d0 * d0 * i0 + d1 * d1 * i1);
      const ushort* xb = A1 + (size_t)r * 1152 + 1024;
      float f0 = bu2f(xb[lane]);
      float f1 = bu2f(xb[64 + lane]);
      #pragma unroll
      for (int k = 0; k < 8; ++k) {
        float wk = __shfl(w, k, 64);
        acc0[k] = fmaf(wk, f0, acc0[k]);
        acc1[k] = fmaf(wk, f1, acc1[k]);
      }
      rec = nxt;
    }
  }
  const float inv = 1.f / fmaxf((float)(e - b), 1.f);
  ushort* zr = A1 + (size_t)n * 1152;
  #pragma unroll
  for (int k = 0; k < 8; ++k) {
    zr[k * 128 + lane] = f2bu(acc0[k] * inv);
    zr[k * 128 + 64 + lane] = f2bu(acc1[k] * inv);
  }
}

// ---- gemm1: h_bf = ELU( A1[N2,1152] @ W1t^T + b1 )  (bf16 MFMA) ----
__global__ __launch_bounds__(256) void gemm1_mfma(
    const ushort* __restrict__ A1, const ushort* __restrict__ W1t,
    const float* __restrict__ bias, ushort* __restrict__ hb) {
  __shared__ ushort As[64 * 32];
  __shared__ ushort Bs[64 * 32];
  const int t = threadIdx.x;
  const int m0 = blockIdx.x * 64;
  const int lane = t & 63, wv = t >> 6;
  const int mfrag = lane & 15, quad = lane >> 4;
  const int arow = t >> 2, achk = t & 3;
  v4f acc[4];
  #pragma unroll
  for (int ct = 0; ct < 4; ++ct) acc[ct] = (v4f){0.f, 0.f, 0.f, 0.f};

  for (int kc = 0; kc < 36; ++kc) {
    const int k0 = kc * 32;
    uint4 av = *(const uint4*)(A1 + (size_t)(m0 + arow) * 1152 + k0 + achk * 8);
    uint4 bv = *(const uint4*)(W1t + (size_t)arow * 1152 + k0 + achk * 8);
    __syncthreads();
    *(uint4*)(As + arow * 32 + achk * 8) = av;
    *(uint4*)(Bs + arow * 32 + achk * 8) = bv;
    __syncthreads();
    v8bf a = ld_frag(As + (16 * wv + mfrag) * 32 + quad * 8);
    #pragma unroll
    for (int ct = 0; ct < 4; ++ct) {
      v8bf bfr = ld_frag(Bs + (ct * 16 + mfrag) * 32 + quad * 8);
      acc[ct] = __builtin_amdgcn_mfma_f32_16x16x32_bf16(a, bfr, acc[ct], 0, 0, 0);
    }
  }
  #pragma unroll
  for (int ct = 0; ct < 4; ++ct) {
    int colh = ct * 16 + mfrag;
    float bcol = bias[colh];
    #pragma unroll
    for (int r = 0; r < 4; ++r) {
      int rowm = m0 + 16 * wv + quad * 4 + r;
      float v = acc[ct][r] + bcol;
      v = v > 0.f ? v : expm1f(v);
      hb[(size_t)rowm * 64 + colh] = f2bu(v);
    }
  }
}

// ---- z2: Z2[c, k*64+f] = (1/deg) sum_e w_ek * h_bf[r_e, f]  (wave/node) ----
__global__ __launch_bounds__(256) void z2_kernel(
    const ushort* __restrict__ hb, ushort* __restrict__ Z2,
    const float4* __restrict__ recs, const int* __restrict__ starts,
    const float* __restrict__ mu, const float* __restrict__ sg, int N) {
  const int lane = threadIdx.x & 63, wv = threadIdx.x >> 6;
  const int n = blockIdx.x * 4 + wv;
  if (n >= N) return;
  const int kk = lane & 7;
  const float m0 = mu[2 * kk], m1 = mu[2 * kk + 1];
  const float s0 = sg[2 * kk], s1 = sg[2 * kk + 1];
  const float i0 = -0.5f / (1e-15f + s0 * s0), i1 = -0.5f / (1e-15f + s1 * s1);
  const int b = starts[n], e = starts[n + 1];
  float acc[8];
  #pragma unroll
  for (int k = 0; k < 8; ++k) acc[k] = 0.f;
  if (b < e) {
    float4 rec = recs[b];
    for (int i = b; i < e; ++i) {
      float4 nxt = rec;
      if (i + 1 < e) nxt = recs[i + 1];
      int r = __float_as_int(rec.x);
      float d0 = rec.y - m0, d1 = rec.z - m1;
      float w = __expf(d0 * d0 * i0 + d1 * d1 * i1);
      float f0 = bu2f(hb[(size_t)r * 64 + lane]);
      #pragma unroll
      for (int k = 0; k < 8; ++k) {
        float wk = __shfl(w, k, 64);
        acc[k] = fmaf(wk, f0, acc[k]);
      }
      rec = nxt;
    }
  }
  const float inv = 1.f / fmaxf((float)(e - b), 1.f);
  ushort* zr = Z2 + (size_t)n * 512;
  #pragma unroll
  for (int k = 0; k < 8; ++k) zr[k * 64 + lane] = f2bu(acc[k] * inv);
}

// ---- gemm2: out = log_softmax( [Z2 | h_bf] @ W2t^T + b2 )  (bf16 MFMA) ----
__global__ __launch_bounds__(256) void gemm2_mfma(
    const ushort* __restrict__ Z2, const ushort* __restrict__ hb,
    const ushort* __restrict__ W2t, const float* __restrict__ bias,
    float* __restrict__ out, int N) {
  __shared__ ushort As[64 * 32];
  __shared__ ushort Bs[16 * 32];
  const int t = threadIdx.x;
  const int m0 = blockIdx.x * 64;
  const int lane = t & 63, wv = t >> 6;
  const int mfrag = lane & 15, quad = lane >> 4;
  const int arow = t >> 2, achk = t & 3;
  v4f acc = (v4f){0.f, 0.f, 0.f, 0.f};

  for (int kc = 0; kc < 18; ++kc) {
    const int k0 = kc * 32;
    uint4 av;
    if (kc < 16)
      av = *(const uint4*)(Z2 + (size_t)(m0 + arow) * 512 + k0 + achk * 8);
    else
      av = *(const uint4*)(hb + (size_t)(m0 + arow) * 64 + (k0 - 512) + achk * 8);
    uint4 bv;
    if (t < 64) bv = *(const uint4*)(W2t + (size_t)(t >> 2) * 576 + k0 + (t & 3) * 8);
    __syncthreads();
    *(uint4*)(As + arow * 32 + achk * 8) = av;
    if (t < 64) *(uint4*)(Bs + (t >> 2) * 32 + (t & 3) * 8) = bv;
    __syncthreads();
    v8bf a = ld_frag(As + (16 * wv + mfrag) * 32 + quad * 8);
    v8bf bfr = ld_frag(Bs + mfrag * 32 + quad * 8);
    acc = __builtin_amdgcn_mfma_f32_16x16x32_bf16(a, bfr, acc, 0, 0, 0);
  }
  const float bcol = bias[mfrag];
  #pragma unroll
  for (int r = 0; r < 4; ++r) {
    float v = acc[r] + bcol;
    float mx = v;
    #pragma unroll
    for (int off = 8; off >= 1; off >>= 1) mx = fmaxf(mx, __shfl_xor(mx, off, 64));
    float sm = __expf(v - mx);
    #pragma unroll
    for (int off = 8; off >= 1; off >>= 1) sm += __shfl_xor(sm, off, 64);
    int rowm = m0 + 16 * wv + quad * 4 + r;
    if (rowm < N) out[(size_t)rowm * 16 + mfrag] = v - mx - __logf(sm);
  }
}

extern "C" void kernel_launch(void* const* d_in, const int* in_sizes, int n_in,
                              void* d_out, int out_size, void* d_ws, size_t ws_size,
                              hipStream_t stream) {
  const float* x     = (const float*)d_in[0];
  const int*   eidx  = (const int*)d_in[1];
  const float* eattr = (const float*)d_in[2];
  const float* g1w   = (const float*)d_in[3];
  const float* mu1   = (const float*)d_in[4];
  const float* sg1   = (const float*)d_in[5];
  const float* r1w   = (const float*)d_in[6];
  const float* b1    = (const float*)d_in[7];
  const float* g2w   = (const float*)d_in[8];
  const float* mu2   = (const float*)d_in[9];
  const float* sg2   = (const float*)d_in[10];
  const float* r2w   = (const float*)d_in[11];
  const float* b2    = (const float*)d_in[12];

  const int N = in_sizes[0] / NF;   // 50000
  const int E = in_sizes[1] / 2;    // 800000
  const int* row = eidx;
  const int* col = eidx + E;
  const int N2 = (N + 63) & ~63;    // 50048 (pad to 64-row GEMM tiles)

  // Workspace layout:
  //   recs : E float4                       12.8 MB
  //   A1   : N2*1152 bf16  (Z1 | x_bf)     115.3 MB  -- after gemm1, low 512
  //          cols are reused as Z2 [N2*512]
  //   hb   : N2*64 bf16                      6.4 MB
  //   W1t  : 64*1152 bf16, W2t : 16*576 bf16
  //   counts/starts/cursor : ints
  float4* recs = (float4*)d_ws;
  ushort* A1   = (ushort*)(recs + (size_t)E);
  ushort* Z2   = A1;                               // alias (after gemm1 done)
  ushort* hb   = A1 + (size_t)N2 * 1152;
  ushort* W1t  = hb + (size_t)N2 * 64;
  ushort* W2t  = W1t + (size_t)64 * 1152;
  int* counts  = (int*)(W2t + (size_t)16 * 576);
  int* starts  = counts + N;
  int* cursor  = starts + N + 1;

  hipMemsetAsync(counts, 0, (size_t)N * sizeof(int), stream);
  hist_kernel<<<(E + 255) / 256, 256, 0, stream>>>(col, counts, E);
  scan_kernel<<<1, 1024, 0, stream>>>(counts, starts, cursor, N);
  fill_kernel<<<(E + 255) / 256, 256, 0, stream>>>(row, col, eattr, cursor, recs, E);

  prep_kernel<<<(64 * 1152 + 16 * 576 + 255) / 256, 256, 0, stream>>>(
      g1w, r1w, g2w, r2w, W1t, W2t);
  cast_x_kernel<<<(N * 32 + 255) / 256, 256, 0, stream>>>(x, A1, N);

  z1_kernel<<<(N + 3) / 4, 256, 0, stream>>>(A1, recs, starts, mu1, sg1, N);
  gemm1_mfma<<<N2 / 64, 256, 0, stream>>>(A1, W1t, b1, hb);
  z2_kernel<<<(N + 3) / 4, 256, 0, stream>>>(hb, Z2, recs, starts, mu2, sg2, N);
  gemm2_mfma<<<N2 / 64, 256, 0, stream>>>(Z2, hb, W2t, b2, (float*)d_out, N);
}